// Round 5
// baseline (169.081 us; speedup 1.0000x reference)
//
#include <hip/hip_runtime.h>

typedef __attribute__((ext_vector_type(8))) short bf16x8;
typedef __attribute__((ext_vector_type(4))) float f32x4;
typedef unsigned int u32;
typedef unsigned short u16;
typedef unsigned long long u64;

#define S0 384
#define PLANE0 (384 * 384)

__device__ __forceinline__ u16 bfr(float f) {   // f32 -> bf16 RNE
    u32 b = __float_as_uint(f);
    b += 0x7fff + ((b >> 16) & 1);
    return (u16)(b >> 16);
}

// ---------------------------------------------------------------------------
// Stage 1: v[k,m,d] = lin0_b[m] + sum_{r<128} lin0_w[m,r] * feats[3r+k, d]
// ---------------------------------------------------------------------------
__global__ void k_v(const float* __restrict__ V,
                    const float* __restrict__ lin0_w,
                    const float* __restrict__ lin0_b,
                    float* __restrict__ v_out) {
    int blk = blockIdx.x;          // 0..194
    int k = blk / 65, m = blk % 65;
    int d = threadIdx.x;           // 0..255
    int t = d >> 5, f = d & 31;
    const float* vbase = V + (size_t)t * 384 * 33 + f;
    float acc = lin0_b[m];
    for (int r = 0; r < 128; ++r) {
        float w = lin0_w[m * 130 + r];
        acc += w * vbase[(3 * r + k) * 33];
    }
    v_out[(size_t)blk * 256 + d] = acc;
}

// ---------------------------------------------------------------------------
// Stage 2: attention scalars A[k,t] (9 floats)
// ---------------------------------------------------------------------------
__global__ void k_att(const float* __restrict__ v,
                      const float* __restrict__ att_w,
                      const float* __restrict__ att_b,
                      const float* __restrict__ agg,
                      float* __restrict__ A_out) {
    int k = blockIdx.x;
    int tid = threadIdx.x;
    __shared__ float wv1[256], wv2[256];
    __shared__ float sbuf[3][65];
    __shared__ float Ck_s;
    __shared__ float sm[3];
    {
        int d = tid;
        float a1 = 0.f, a2 = 0.f;
        for (int h = 0; h < 64; ++h) {
            float w = att_w[((size_t)(k * 64 + h)) * 256 + d];
            a1 += agg[k * 128 + h] * w;
            a2 += agg[k * 128 + 64 + h] * w;
        }
        wv1[d] = a1;
        wv2[d] = a2;
    }
    if (tid == 0) {
        float c = 0.f;
        for (int h = 0; h < 64; ++h)
            c += (agg[k * 128 + h] + agg[k * 128 + 64 + h]) * att_b[k * 64 + h];
        Ck_s = c;
    }
    __syncthreads();
    if (tid < 195) {
        int t = tid / 65, m = tid % 65;
        const float* vt = v + ((size_t)(t * 65 + m)) * 256;
        const float* vk = v + ((size_t)(k * 65 + m)) * 256;
        float s = Ck_s;
        for (int d = 0; d < 256; ++d)
            s += vt[d] * wv1[d] + vk[d] * wv2[d];
        s = s > 0.f ? s : 0.01f * s;
        sbuf[t][m] = s;
    }
    __syncthreads();
    if (tid < 3) {
        float mx = sbuf[tid][0];
        for (int m = 1; m < 65; ++m) mx = fmaxf(mx, sbuf[tid][m]);
        sm[tid] = mx;
    }
    __syncthreads();
    if (tid == 0) {
        float mx = fmaxf(sm[0], fmaxf(sm[1], sm[2]));
        float e0 = __expf(sm[0] - mx), e1 = __expf(sm[1] - mx), e2 = __expf(sm[2] - mx);
        float inv = 1.f / (e0 + e1 + e2);
        A_out[k * 3 + 0] = e0 * inv;
        A_out[k * 3 + 1] = e1 * inv;
        A_out[k * 3 + 2] = e2 * inv;
    }
}

// ---------------------------------------------------------------------------
// Composed-conv weight prep: E[o, tap, i] (bf16), tap=(dy*3+dx), and
// b_eff[o] = cb[o] + sum_m cb[m]*sum(W[o][m][:][:]).
// ---------------------------------------------------------------------------
__global__ void k_prep_E(const float* __restrict__ cw, const float* __restrict__ cb,
                         u16* __restrict__ Ebf, float* __restrict__ beff) {
    int o = blockIdx.x, i = threadIdx.x;
    __shared__ float4 Wo[128];
    __shared__ float red[128];
    Wo[i] = *(const float4*)(cw + (size_t)(o * 128 + i) * 4);
    __syncthreads();
    float a9[9];
#pragma unroll
    for (int q = 0; q < 9; ++q) a9[q] = 0.f;
    for (int m = 0; m < 128; ++m) {
        float4 w1 = *(const float4*)(cw + (size_t)(m * 128 + i) * 4);  // W[m][i]
        float4 w2 = Wo[m];                                             // W[o][m]
        a9[0] += w2.x * w1.x;
        a9[1] += w2.x * w1.y + w2.y * w1.x;
        a9[2] += w2.y * w1.y;
        a9[3] += w2.x * w1.z + w2.z * w1.x;
        a9[4] += w2.x * w1.w + w2.y * w1.z + w2.z * w1.y + w2.w * w1.x;
        a9[5] += w2.y * w1.w + w2.w * w1.y;
        a9[6] += w2.z * w1.z;
        a9[7] += w2.z * w1.w + w2.w * w1.z;
        a9[8] += w2.w * w1.w;
    }
#pragma unroll
    for (int q = 0; q < 9; ++q)
        Ebf[(size_t)o * 1152 + q * 128 + i] = bfr(a9[q]);
    float4 wo = Wo[i];
    red[i] = cb[i] * (wo.x + wo.y + wo.z + wo.w);
    __syncthreads();
    for (int s = 64; s > 0; s >>= 1) {
        if (i < s) red[i] += red[i + s];
        __syncthreads();
    }
    if (i == 0) beff[o] = cb[o] + red[0];
}

// ---------------------------------------------------------------------------
// Fused 3x3 conv (composed 2x2∘2x2) on pad2(graph*att9).
// Block: 128 oc x 32 px x 2 rows.  K = 1152, split in 2 ic-half phases.
// LDS: [row 0..3][px 0..33][64 ic] bf16, swizzle byte=((r*34+p)<<7)+((h^(p&7))<<4)
// Pipeline: load ph0 -> pack/write ph0 -> issue ph1 loads -> bar -> MFMA ph0
//           (per-tap A prefetch) -> bar -> pack/write ph1 -> bar -> MFMA ph1.
// Grid: 2304 1D, bijective XCD chunk swizzle (2304 = 8 x 288).
// ---------------------------------------------------------------------------
__global__ __launch_bounds__(256) void k_conv9(
        const float* __restrict__ graph,
        const short* __restrict__ Ebf,
        const float* __restrict__ A9g,
        const float* __restrict__ beff,
        const float* __restrict__ pl,
        float* __restrict__ out) {
    __shared__ __align__(16) char BtB[17408];
    const int tid = threadIdx.x;
    const int lane = tid & 63, wave = tid >> 6;
    const int l15 = lane & 15, l16 = lane >> 4;

    // XCD chunk swizzle: consecutive logical blocks (same/adjacent y) per XCD
    const int phys = blockIdx.x;                       // 0..2303
    const int logical = (phys & 7) * 288 + (phys >> 3);
    const int bx = logical % 12, by = logical / 12;
    const int x0 = bx * 32, y0 = by * 2;
    const int ocbase = wave * 32;

    const int spx = tid & 31;          // staging px 0..31
    const int soct = tid >> 5;         // staging ic-octet 0..7

    // row factors & offsets
    int rowoff[4];
    float fr[4][3];
#pragma unroll
    for (int r = 0; r < 4; ++r) {
        int y = y0 + r;
        bool rv = y < S0;
        rowoff[r] = (rv ? y : S0 - 1) * S0;
        int ym = y % 3;
        fr[r][0] = rv ? A9g[ym * 3 + 0] : 0.f;
        fr[r][1] = rv ? A9g[ym * 3 + 1] : 0.f;
        fr[r][2] = rv ? A9g[ym * 3 + 2] : 0.f;
    }
    float fct[4];
    {
        int xm = (x0 + spx) % 3;
#pragma unroll
        for (int r = 0; r < 4; ++r) fct[r] = fr[r][xm];
    }
    const float* gmain = graph + (size_t)(soct * 8) * PLANE0 + x0 + spx;
    const int wmain = (spx << 7) + ((soct ^ (spx & 7)) << 4);

    // extra columns px 32,33 handled by threads 0..63 (one unit each)
    const float* gext = nullptr;
    float efct = 0.f;
    int ewaddr = 0;
    if (tid < 64) {
        int erow = tid >> 4;
        int epx = 32 + ((tid >> 3) & 1);
        int eoct = tid & 7;
        int ex = x0 + epx;
        bool ev = ex < S0;
        int ecx = ev ? ex : S0 - 1;
        int exm = ex % 3;
        efct = ev ? fr[erow][exm] : 0.f;
        gext = graph + (size_t)(eoct * 8) * PLANE0 + rowoff[erow] + ecx;
        ewaddr = ((erow * 34 + epx) << 7) + ((eoct ^ (epx & 7)) << 4);
    }

    f32x4 acc[2][2][2];   // [t2][mi][ni]
#pragma unroll
    for (int a = 0; a < 2; ++a)
#pragma unroll
        for (int b = 0; b < 2; ++b)
#pragma unroll
            for (int c = 0; c < 2; ++c)
                acc[a][b][c] = (f32x4){0.f, 0.f, 0.f, 0.f};

    // ---- load phase 0 ----
    float s0[4][8], se0[8];
#pragma unroll
    for (int r = 0; r < 4; ++r)
#pragma unroll
        for (int e = 0; e < 8; ++e)
            s0[r][e] = gmain[(size_t)e * PLANE0 + rowoff[r]];
    if (tid < 64) {
#pragma unroll
        for (int e = 0; e < 8; ++e) se0[e] = gext[(size_t)e * PLANE0];
    }

    // ---- pack + write phase 0 ----
#pragma unroll
    for (int r = 0; r < 4; ++r) {
        uint4 w;
        w.x = (u32)bfr(s0[r][0] * fct[r]) | ((u32)bfr(s0[r][1] * fct[r]) << 16);
        w.y = (u32)bfr(s0[r][2] * fct[r]) | ((u32)bfr(s0[r][3] * fct[r]) << 16);
        w.z = (u32)bfr(s0[r][4] * fct[r]) | ((u32)bfr(s0[r][5] * fct[r]) << 16);
        w.w = (u32)bfr(s0[r][6] * fct[r]) | ((u32)bfr(s0[r][7] * fct[r]) << 16);
        *(uint4*)(BtB + ((r * 34) << 7) + wmain) = w;
    }
    if (tid < 64) {
        uint4 w;
        w.x = (u32)bfr(se0[0] * efct) | ((u32)bfr(se0[1] * efct) << 16);
        w.y = (u32)bfr(se0[2] * efct) | ((u32)bfr(se0[3] * efct) << 16);
        w.z = (u32)bfr(se0[4] * efct) | ((u32)bfr(se0[5] * efct) << 16);
        w.w = (u32)bfr(se0[6] * efct) | ((u32)bfr(se0[7] * efct) << 16);
        *(uint4*)(BtB + ewaddr) = w;
    }

    // ---- issue phase-1 loads early (consumed after MFMA ph0) ----
    float s1[4][8], se1[8];
#pragma unroll
    for (int r = 0; r < 4; ++r)
#pragma unroll
        for (int e = 0; e < 8; ++e)
            s1[r][e] = gmain[(size_t)(64 + e) * PLANE0 + rowoff[r]];
    if (tid < 64) {
#pragma unroll
        for (int e = 0; e < 8; ++e) se1[e] = gext[(size_t)(64 + e) * PLANE0];
    }

    __syncthreads();

    // ---- MFMA section with per-tap A-frag prefetch ----
    auto do_mfma = [&](int ph) {
        const short* Ab = Ebf + (size_t)(ocbase + l15) * 1152 + ph * 64 + l16 * 8;
        bf16x8 fa[2][2], fn[2][2];   // [icg][mi]
#pragma unroll
        for (int icg = 0; icg < 2; ++icg)
#pragma unroll
            for (int mi = 0; mi < 2; ++mi)
                fa[icg][mi] = *(const bf16x8*)(Ab + icg * 32 + mi * (16 * 1152));
#pragma unroll
        for (int tap = 0; tap < 9; ++tap) {
            if (tap < 8) {
#pragma unroll
                for (int icg = 0; icg < 2; ++icg)
#pragma unroll
                    for (int mi = 0; mi < 2; ++mi)
                        fn[icg][mi] = *(const bf16x8*)(Ab + (tap + 1) * 128
                                                       + icg * 32 + mi * (16 * 1152));
            }
            const int dy = tap / 3, dx = tap % 3;
            const int pbase = l15 + dx;
            const int pswz = (pbase & 7);
#pragma unroll
            for (int icg = 0; icg < 2; ++icg) {
                const int sz = ((icg * 4 + l16) ^ pswz) << 4;
#pragma unroll
                for (int t2 = 0; t2 < 2; ++t2) {
#pragma unroll
                    for (int ni = 0; ni < 2; ++ni) {
                        bf16x8 bv = *(const bf16x8*)(BtB
                            + (((t2 + dy) * 34 + ni * 16 + pbase) << 7) + sz);
                        acc[t2][0][ni] = __builtin_amdgcn_mfma_f32_16x16x32_bf16(fa[icg][0], bv, acc[t2][0][ni], 0, 0, 0);
                        acc[t2][1][ni] = __builtin_amdgcn_mfma_f32_16x16x32_bf16(fa[icg][1], bv, acc[t2][1][ni], 0, 0, 0);
                    }
                }
            }
#pragma unroll
            for (int icg = 0; icg < 2; ++icg)
#pragma unroll
                for (int mi = 0; mi < 2; ++mi)
                    fa[icg][mi] = fn[icg][mi];
        }
    };

    do_mfma(0);
    __syncthreads();

    // ---- pack + write phase 1 ----
#pragma unroll
    for (int r = 0; r < 4; ++r) {
        uint4 w;
        w.x = (u32)bfr(s1[r][0] * fct[r]) | ((u32)bfr(s1[r][1] * fct[r]) << 16);
        w.y = (u32)bfr(s1[r][2] * fct[r]) | ((u32)bfr(s1[r][3] * fct[r]) << 16);
        w.z = (u32)bfr(s1[r][4] * fct[r]) | ((u32)bfr(s1[r][5] * fct[r]) << 16);
        w.w = (u32)bfr(s1[r][6] * fct[r]) | ((u32)bfr(s1[r][7] * fct[r]) << 16);
        *(uint4*)(BtB + ((r * 34) << 7) + wmain) = w;
    }
    if (tid < 64) {
        uint4 w;
        w.x = (u32)bfr(se1[0] * efct) | ((u32)bfr(se1[1] * efct) << 16);
        w.y = (u32)bfr(se1[2] * efct) | ((u32)bfr(se1[3] * efct) << 16);
        w.z = (u32)bfr(se1[4] * efct) | ((u32)bfr(se1[5] * efct) << 16);
        w.w = (u32)bfr(se1[6] * efct) | ((u32)bfr(se1[7] * efct) << 16);
        *(uint4*)(BtB + ewaddr) = w;
    }
    __syncthreads();

    do_mfma(1);

    // ---- epilogue: out = relu(pl*(acc + beff) + graph) ----
    float plv = pl[0];
#pragma unroll
    for (int t2 = 0; t2 < 2; ++t2) {
        int yy = y0 + t2;
#pragma unroll
        for (int mi = 0; mi < 2; ++mi) {
#pragma unroll
            for (int r4 = 0; r4 < 4; ++r4) {
                int oc = ocbase + mi * 16 + l16 * 4 + r4;
                float bias = beff[oc];
                const float* grow = graph + (size_t)oc * PLANE0 + (size_t)yy * S0 + x0;
                float* orow = out + (size_t)oc * PLANE0 + (size_t)yy * S0 + x0;
#pragma unroll
                for (int ni = 0; ni < 2; ++ni) {
                    int xx = ni * 16 + l15;
                    float v = plv * (acc[t2][mi][ni][r4] + bias) + grow[xx];
                    orow[xx] = v > 0.f ? v : 0.f;
                }
            }
        }
    }
}

// ---------------------------------------------------------------------------
extern "C" void kernel_launch(void* const* d_in, const int* in_sizes, int n_in,
                              void* d_out, int out_size, void* d_ws, size_t ws_size,
                              hipStream_t stream) {
    (void)in_sizes; (void)n_in; (void)out_size; (void)ws_size;
    const float* V      = (const float*)d_in[0];
    const float* graph  = (const float*)d_in[1];
    const float* lin0_w = (const float*)d_in[4];
    const float* lin0_b = (const float*)d_in[5];
    const float* att_w  = (const float*)d_in[6];
    const float* att_b  = (const float*)d_in[7];
    const float* agg    = (const float*)d_in[8];
    const float* pl     = (const float*)d_in[9];
    const float* cw     = (const float*)d_in[10];
    const float* cb     = (const float*)d_in[11];
    float* out = (float*)d_out;

    char* ws = (char*)d_ws;
    float* v_ws = (float*)ws;                       // 3*65*256 f32 (199680 B)
    float* A_ws = (float*)(ws + 200704);            // 9 f32
    u16*   Ebf  = (u16*)(ws + 200768);              // 128*1152 bf16 = 294912 B
    float* beff = (float*)(ws + 495680);            // 128 f32

    k_prep_E<<<128, 128, 0, stream>>>(cw, cb, Ebf, beff);
    k_v<<<195, 256, 0, stream>>>(V, lin0_w, lin0_b, v_ws);
    k_att<<<3, 256, 0, stream>>>(v_ws, att_w, att_b, agg, A_ws);
    k_conv9<<<2304, 256, 0, stream>>>(
        graph, (const short*)Ebf, A_ws, beff, pl, out);
}